// Round 2
// baseline (380.912 us; speedup 1.0000x reference)
//
#include <hip/hip_runtime.h>
#include <hip/hip_bf16.h>

#define BS 4
#define QLEN 2048
#define DIM 1024
#define NH 16
#define DH 64

typedef __attribute__((ext_vector_type(8))) short bf16x8;
typedef __attribute__((ext_vector_type(4))) float f32x4;
typedef unsigned short u16;
typedef unsigned int u32;
typedef unsigned long long u64;

__device__ __forceinline__ u16 f2bf(float f) {
    u32 u = __builtin_bit_cast(u32, f);
    u32 r = (u + 0x7FFFu + ((u >> 16) & 1u)) >> 16;
    return (u16)r;
}

// async global->LDS, 16B per lane. LDS dest must be wave-uniform base; HW adds lane*16.
__device__ __forceinline__ void async_lds16(const void* gp, void* lp) {
    __builtin_amdgcn_global_load_lds(
        (const __attribute__((address_space(1))) u32*)(u64)gp,
        (__attribute__((address_space(3))) u32*)(u32)(u64)lp,
        16, 0, 0);
}

// ---------------- fp32 -> bf16 conversion ----------------
__global__ void cvt_kernel(const float* __restrict__ src, u16* __restrict__ dst, int n4) {
    int i = blockIdx.x * blockDim.x + threadIdx.x;
    if (i < n4) {
        float4 v = ((const float4*)src)[i];
        ushort4 o;
        o.x = f2bf(v.x); o.y = f2bf(v.y); o.z = f2bf(v.z); o.w = f2bf(v.w);
        ((ushort4*)dst)[i] = o;
    }
}

// ---------------- BT GEMM: C[m,n] = sum_k A[m,k]*W[n,k] + bias[n] ----------------
// mode 0: write bf16 to QKV layout [bh][q][d] with scale
// mode 1: write fp32 row-major to ofp
// mode 2: write bf16 transposed to [bh][d][q] (for V)
__global__ __launch_bounds__(256) void gemm_bt(
    const u16* __restrict__ A, const u16* __restrict__ W,
    const float* __restrict__ bias, int M, int N, int K,
    int mode, float scale, u16* __restrict__ obf, float* __restrict__ ofp)
{
    __shared__ __align__(16) u16 As[128 * 32];
    __shared__ __align__(16) u16 Bs[128 * 32];
    const int t = threadIdx.x;
    const int w = t >> 6, lane = t & 63;
    const int lr = lane & 15, lg = lane >> 4;
    const int m0 = blockIdx.y * 128, n0 = blockIdx.x * 128;
    const int wm = (w >> 1) * 64, wn = (w & 1) * 64;
    const int srow = w * 16 + (lane >> 2);   // staging row (+c*64)
    const int sk = (lane & 3) * 8;           // staging k-offset (elems)

    f32x4 acc[4][4] = {};

    for (int kt = 0; kt < K; kt += 32) {
        __syncthreads();
        async_lds16(A + (u64)(m0 + srow) * K + kt + sk,        &As[(w * 16) * 32]);
        async_lds16(A + (u64)(m0 + 64 + srow) * K + kt + sk,   &As[(64 + w * 16) * 32]);
        async_lds16(W + (u64)(n0 + srow) * K + kt + sk,        &Bs[(w * 16) * 32]);
        async_lds16(W + (u64)(n0 + 64 + srow) * K + kt + sk,   &Bs[(64 + w * 16) * 32]);
        __syncthreads();
        bf16x8 a[4], b[4];
#pragma unroll
        for (int i = 0; i < 4; ++i) a[i] = *(const bf16x8*)&As[(wm + i * 16 + lr) * 32 + lg * 8];
#pragma unroll
        for (int i = 0; i < 4; ++i) b[i] = *(const bf16x8*)&Bs[(wn + i * 16 + lr) * 32 + lg * 8];
#pragma unroll
        for (int mi = 0; mi < 4; ++mi)
#pragma unroll
            for (int ni = 0; ni < 4; ++ni)
                acc[mi][ni] = __builtin_amdgcn_mfma_f32_16x16x32_bf16(a[mi], b[ni], acc[mi][ni], 0, 0, 0);
    }

#pragma unroll
    for (int mi = 0; mi < 4; ++mi)
#pragma unroll
        for (int ni = 0; ni < 4; ++ni) {
            const int col = n0 + wn + ni * 16 + lr;
            const float bv = bias[col];
#pragma unroll
            for (int r = 0; r < 4; ++r) {
                const int row = m0 + wm + mi * 16 + lg * 4 + r;
                float v = acc[mi][ni][r] + bv;
                if (mode == 1) {
                    ofp[(u64)row * N + col] = v;
                } else {
                    const int bh = (row >> 11) * NH + (col >> 6);
                    const int q = row & (QLEN - 1);
                    const int d = col & (DH - 1);
                    if (mode == 0) {
                        obf[((u64)bh * QLEN + q) * DH + d] = f2bf(v * scale);
                    } else {  // mode 2: V transposed
                        obf[((u64)bh * DH + d) * QLEN + q] = f2bf(v);
                    }
                }
            }
        }
}

// ---------------- Flash attention ----------------
// grid (QLEN/64, BS*NH); 4 waves, each owns 16 q-rows.
__global__ __launch_bounds__(256) void attn_kernel(
    const u16* __restrict__ Qb, const u16* __restrict__ Kb, const u16* __restrict__ Vt,
    const int* __restrict__ mask, u16* __restrict__ ctx)
{
    __shared__ __align__(16) u16 Ks[64 * 64];      // [krow][d], XOR-swizzled image
    __shared__ __align__(16) u16 Vs[64 * 64];      // [d][k],   XOR-swizzled image
    __shared__ __align__(16) u16 Pl[4][16 * 72];   // per-wave P [qlocal][klocal], stride 72

    const int t = threadIdx.x;
    const int w = t >> 6, lane = t & 63;
    const int lr = lane & 15, lg = lane >> 4;
    const int bh = blockIdx.y;
    const int b = bh >> 4, hh = bh & 15;
    const int q0 = blockIdx.x * 64;

    // Q fragments (held in registers for the whole block)
    const int qrow = q0 + w * 16 + lr;
    bf16x8 aq[2];
#pragma unroll
    for (int kk = 0; kk < 2; ++kk)
        aq[kk] = *(const bf16x8*)&Qb[((u64)bh * QLEN + qrow) * DH + kk * 32 + lg * 8];

    f32x4 o[4] = {};
    float mrun[4], lrun[4];
#pragma unroll
    for (int r = 0; r < 4; ++r) { mrun[r] = -3.0e38f; lrun[r] = 0.f; }

    const int srow = lane >> 3;        // + c*32 + w*8
    const int schunk = lane & 7;

    for (int kt = 0; kt < QLEN; kt += 64) {
        __syncthreads();
#pragma unroll
        for (int c = 0; c < 2; ++c) {
            const int row = c * 32 + w * 8 + srow;
            const int chunk = schunk ^ (row & 7);  // pre-swizzled source
            async_lds16(Kb + ((u64)bh * QLEN + kt + row) * DH + chunk * 8, &Ks[(c * 32 + w * 8) * 64]);
            async_lds16(Vt + ((u64)bh * DH + row) * QLEN + kt + chunk * 8, &Vs[(c * 32 + w * 8) * 64]);
        }
        __syncthreads();

        // S = Q K^T  (per wave: 16 q-rows x 64 k-cols)
        f32x4 s[4] = {};
#pragma unroll
        for (int nf = 0; nf < 4; ++nf) {
            const int row = nf * 16 + lr;
#pragma unroll
            for (int kk = 0; kk < 2; ++kk) {
                const u32 off = ((u32)(row * 128 + kk * 64 + lg * 16)) ^ ((u32)(row & 7) << 4);
                bf16x8 bk = *(const bf16x8*)((const char*)Ks + off);
                s[nf] = __builtin_amdgcn_mfma_f32_16x16x32_bf16(aq[kk], bk, s[nf], 0, 0, 0);
            }
        }
        // mask (col = kt + nf*16 + lr)
#pragma unroll
        for (int nf = 0; nf < 4; ++nf) {
            if (mask[b * QLEN + kt + nf * 16 + lr] == 0) {
                s[nf][0] = -3.0e38f; s[nf][1] = -3.0e38f; s[nf][2] = -3.0e38f; s[nf][3] = -3.0e38f;
            }
        }
        // online softmax: row r lives across the 16 lanes sharing lg
        float pr[4][4];
        float corr[4];
#pragma unroll
        for (int r = 0; r < 4; ++r) {
            float tm = fmaxf(fmaxf(s[0][r], s[1][r]), fmaxf(s[2][r], s[3][r]));
#pragma unroll
            for (int off = 1; off < 16; off <<= 1) tm = fmaxf(tm, __shfl_xor(tm, off));
            const float nm = fmaxf(mrun[r], tm);
            corr[r] = __expf(mrun[r] - nm);
            mrun[r] = nm;
            float rs = 0.f;
#pragma unroll
            for (int nf = 0; nf < 4; ++nf) { float p = __expf(s[nf][r] - nm); pr[nf][r] = p; rs += p; }
#pragma unroll
            for (int off = 1; off < 16; off <<= 1) rs += __shfl_xor(rs, off);
            lrun[r] = lrun[r] * corr[r] + rs;
        }
        // P -> LDS (bf16), per-wave private region
#pragma unroll
        for (int nf = 0; nf < 4; ++nf)
#pragma unroll
            for (int r = 0; r < 4; ++r)
                Pl[w][(lg * 4 + r) * 72 + nf * 16 + lr] = f2bf(pr[nf][r]);
        // rescale O
#pragma unroll
        for (int nf = 0; nf < 4; ++nf)
#pragma unroll
            for (int r = 0; r < 4; ++r) o[nf][r] *= corr[r];
        // P A-fragments
        bf16x8 ap[2];
#pragma unroll
        for (int kk = 0; kk < 2; ++kk)
            ap[kk] = *(const bf16x8*)&Pl[w][lr * 72 + kk * 32 + lg * 8];
        // O += P V
#pragma unroll
        for (int nf = 0; nf < 4; ++nf) {
            const int row = nf * 16 + lr;
#pragma unroll
            for (int kk = 0; kk < 2; ++kk) {
                const u32 off = ((u32)(row * 128 + kk * 64 + lg * 16)) ^ ((u32)(row & 7) << 4);
                bf16x8 bv = *(const bf16x8*)((const char*)Vs + off);
                o[nf] = __builtin_amdgcn_mfma_f32_16x16x32_bf16(ap[kk], bv, o[nf], 0, 0, 0);
            }
        }
    }

    // epilogue: normalize, write ctx[b][q][h][d]
#pragma unroll
    for (int r = 0; r < 4; ++r) lrun[r] = 1.0f / fmaxf(lrun[r], 1e-37f);
#pragma unroll
    for (int nf = 0; nf < 4; ++nf)
#pragma unroll
        for (int r = 0; r < 4; ++r) {
            const int q = q0 + w * 16 + lg * 4 + r;
            const int d = nf * 16 + lr;
            ctx[(((u64)b * QLEN + q) * NH + hh) * DH + d] = f2bf(o[nf][r] * lrun[r]);
        }
}

extern "C" void kernel_launch(void* const* d_in, const int* in_sizes, int n_in,
                              void* d_out, int out_size, void* d_ws, size_t ws_size,
                              hipStream_t stream) {
    const float* H    = (const float*)d_in[0];
    const int*   mask = (const int*)d_in[1];
    const float* Wq   = (const float*)d_in[2];
    const float* bq   = (const float*)d_in[3];
    const float* Wk   = (const float*)d_in[4];
    const float* bk   = (const float*)d_in[5];
    const float* Wv   = (const float*)d_in[6];
    const float* bv   = (const float*)d_in[7];
    const float* Wo   = (const float*)d_in[8];
    const float* bo   = (const float*)d_in[9];
    float* out = (float*)d_out;

    const u64 NTOK = (u64)BS * QLEN;        // 8192
    const u64 HN = NTOK * DIM;              // 8388608
    const u64 WN = (u64)DIM * DIM;          // 1048576

    u16* Hb  = (u16*)d_ws;
    u16* Wqb = Hb + HN;
    u16* Wkb = Wqb + WN;
    u16* Wvb = Wkb + WN;
    u16* Wob = Wvb + WN;
    u16* Qb  = Wob + WN;
    u16* Kb  = Qb + HN;
    u16* Vtg = Kb + HN;   // V stored transposed [bh][d][q]
    u16* Ctx = Vtg + HN;

    cvt_kernel<<<(int)(HN / 4 / 256), 256, 0, stream>>>(H, Hb, (int)(HN / 4));
    cvt_kernel<<<(int)(WN / 4 / 256), 256, 0, stream>>>(Wq, Wqb, (int)(WN / 4));
    cvt_kernel<<<(int)(WN / 4 / 256), 256, 0, stream>>>(Wk, Wkb, (int)(WN / 4));
    cvt_kernel<<<(int)(WN / 4 / 256), 256, 0, stream>>>(Wv, Wvb, (int)(WN / 4));
    cvt_kernel<<<(int)(WN / 4 / 256), 256, 0, stream>>>(Wo, Wob, (int)(WN / 4));

    dim3 gg(DIM / 128, (int)(NTOK / 128));  // (8, 64)
    gemm_bt<<<gg, 256, 0, stream>>>(Hb, Wqb, bq, (int)NTOK, DIM, DIM, 0, 0.125f, Qb, nullptr);
    gemm_bt<<<gg, 256, 0, stream>>>(Hb, Wkb, bk, (int)NTOK, DIM, DIM, 0, 1.0f, Kb, nullptr);
    gemm_bt<<<gg, 256, 0, stream>>>(Hb, Wvb, bv, (int)NTOK, DIM, DIM, 2, 1.0f, Vtg, nullptr);

    attn_kernel<<<dim3(QLEN / 64, BS * NH), 256, 0, stream>>>(Qb, Kb, Vtg, mask, Ctx);

    gemm_bt<<<gg, 256, 0, stream>>>(Ctx, Wob, bo, (int)NTOK, DIM, DIM, 1, 1.0f, nullptr, out);
}

// Round 3
// 255.298 us; speedup vs baseline: 1.4920x; 1.4920x over previous
//
#include <hip/hip_runtime.h>
#include <hip/hip_bf16.h>

#define BS 4
#define QLEN 2048
#define DIM 1024
#define NH 16
#define DH 64

typedef __attribute__((ext_vector_type(8))) short bf16x8;
typedef __attribute__((ext_vector_type(4))) float f32x4;
typedef unsigned short u16;
typedef unsigned int u32;
typedef unsigned long long u64;

// hardware packed f32->bf16 (RNE), one instruction
__device__ __forceinline__ u32 cvtpk_bf16(float lo, float hi) {
    u32 r;
    asm("v_cvt_pk_bf16_f32 %0, %1, %2" : "=v"(r) : "v"(lo), "v"(hi));
    return r;
}
__device__ __forceinline__ u16 f2bf_hw(float f) { return (u16)cvtpk_bf16(f, f); }

// async global->LDS, 16B per lane. LDS dest must be wave-uniform base; HW adds lane*16.
__device__ __forceinline__ void async_lds16(const void* gp, void* lp) {
    __builtin_amdgcn_global_load_lds(
        (const __attribute__((address_space(1))) u32*)(u64)gp,
        (__attribute__((address_space(3))) u32*)(u32)(u64)lp,
        16, 0, 0);
}

// ---------------- fused fp32 -> bf16 conversion (H + 4 weights) ----------------
__global__ void cvt_fused(const float* __restrict__ H,
                          const float* __restrict__ W0, const float* __restrict__ W1,
                          const float* __restrict__ W2, const float* __restrict__ W3,
                          u16* __restrict__ Hb,
                          u16* __restrict__ D0, u16* __restrict__ D1,
                          u16* __restrict__ D2, u16* __restrict__ D3) {
    const int h4 = (BS * QLEN * DIM) / 4;   // 2097152
    int i = blockIdx.x * blockDim.x + threadIdx.x;
    const float* s;
    u16* d;
    int off;
    if (i < h4) { s = H; d = Hb; off = i; }
    else {
        int j = i - h4;
        int ws = j >> 18;                    // w4 = 262144 = 2^18
        off = j & 262143;
        s = ws == 0 ? W0 : ws == 1 ? W1 : ws == 2 ? W2 : W3;
        d = ws == 0 ? D0 : ws == 1 ? D1 : ws == 2 ? D2 : D3;
    }
    float4 v = ((const float4*)s)[off];
    u32 lo = cvtpk_bf16(v.x, v.y), hi = cvtpk_bf16(v.z, v.w);
    uint2 o; o.x = lo; o.y = hi;
    ((uint2*)d)[off] = o;
}

// ---------------- fused QKV projection GEMM ----------------
// C[m,n] = sum_k Hb[m,k]*W[n,k] + bias[n]; z selects W/bias/output+layout.
__global__ __launch_bounds__(256) void gemm_qkv(
    const u16* __restrict__ Hb,
    const u16* __restrict__ Wq, const u16* __restrict__ Wk, const u16* __restrict__ Wv,
    const float* __restrict__ bq, const float* __restrict__ bk, const float* __restrict__ bvv,
    u16* __restrict__ Qb, u16* __restrict__ Kb, u16* __restrict__ Vt)
{
    __shared__ __align__(16) u16 As[128 * 32];
    __shared__ __align__(16) u16 Bs[128 * 32];
    const int z = blockIdx.z;
    const u16* W = z == 0 ? Wq : z == 1 ? Wk : Wv;
    const float* bias = z == 0 ? bq : z == 1 ? bk : bvv;
    const int t = threadIdx.x;
    const int w = t >> 6, lane = t & 63;
    const int lr = lane & 15, lg = lane >> 4;
    const int m0 = blockIdx.y * 128, n0 = blockIdx.x * 128;
    const int wm = (w >> 1) * 64, wn = (w & 1) * 64;
    const int srow = w * 16 + (lane >> 2);
    const int sk = (lane & 3) * 8;

    f32x4 acc[4][4] = {};

    for (int kt = 0; kt < DIM; kt += 32) {
        __syncthreads();
        async_lds16(Hb + (u64)(m0 + srow) * DIM + kt + sk,      &As[(w * 16) * 32]);
        async_lds16(Hb + (u64)(m0 + 64 + srow) * DIM + kt + sk, &As[(64 + w * 16) * 32]);
        async_lds16(W + (u64)(n0 + srow) * DIM + kt + sk,       &Bs[(w * 16) * 32]);
        async_lds16(W + (u64)(n0 + 64 + srow) * DIM + kt + sk,  &Bs[(64 + w * 16) * 32]);
        __syncthreads();
        bf16x8 a[4], b[4];
#pragma unroll
        for (int i = 0; i < 4; ++i) a[i] = *(const bf16x8*)&As[(wm + i * 16 + lr) * 32 + lg * 8];
#pragma unroll
        for (int i = 0; i < 4; ++i) b[i] = *(const bf16x8*)&Bs[(wn + i * 16 + lr) * 32 + lg * 8];
#pragma unroll
        for (int mi = 0; mi < 4; ++mi)
#pragma unroll
            for (int ni = 0; ni < 4; ++ni)
                acc[mi][ni] = __builtin_amdgcn_mfma_f32_16x16x32_bf16(a[mi], b[ni], acc[mi][ni], 0, 0, 0);
    }

#pragma unroll
    for (int mi = 0; mi < 4; ++mi)
#pragma unroll
        for (int ni = 0; ni < 4; ++ni) {
            const int col = n0 + wn + ni * 16 + lr;
            const float bb = bias[col];
#pragma unroll
            for (int r = 0; r < 4; ++r) {
                const int row = m0 + wm + mi * 16 + lg * 4 + r;
                const float v = acc[mi][ni][r] + bb;
                const int bh = (row >> 11) * NH + (col >> 6);
                const int q = row & (QLEN - 1);
                const int d = col & (DH - 1);
                if (z == 0)      Qb[((u64)bh * QLEN + q) * DH + d] = f2bf_hw(v * 0.125f);
                else if (z == 1) Kb[((u64)bh * QLEN + q) * DH + d] = f2bf_hw(v);
                else             Vt[((u64)bh * DH + d) * QLEN + q] = f2bf_hw(v);
            }
        }
}

// ---------------- output projection GEMM (fp32 out) ----------------
__global__ __launch_bounds__(256) void gemm_o(
    const u16* __restrict__ A, const u16* __restrict__ W,
    const float* __restrict__ bias, float* __restrict__ ofp)
{
    __shared__ __align__(16) u16 As[128 * 32];
    __shared__ __align__(16) u16 Bs[128 * 32];
    const int t = threadIdx.x;
    const int w = t >> 6, lane = t & 63;
    const int lr = lane & 15, lg = lane >> 4;
    const int m0 = blockIdx.y * 128, n0 = blockIdx.x * 128;
    const int wm = (w >> 1) * 64, wn = (w & 1) * 64;
    const int srow = w * 16 + (lane >> 2);
    const int sk = (lane & 3) * 8;

    f32x4 acc[4][4] = {};

    for (int kt = 0; kt < DIM; kt += 32) {
        __syncthreads();
        async_lds16(A + (u64)(m0 + srow) * DIM + kt + sk,      &As[(w * 16) * 32]);
        async_lds16(A + (u64)(m0 + 64 + srow) * DIM + kt + sk, &As[(64 + w * 16) * 32]);
        async_lds16(W + (u64)(n0 + srow) * DIM + kt + sk,      &Bs[(w * 16) * 32]);
        async_lds16(W + (u64)(n0 + 64 + srow) * DIM + kt + sk, &Bs[(64 + w * 16) * 32]);
        __syncthreads();
        bf16x8 a[4], b[4];
#pragma unroll
        for (int i = 0; i < 4; ++i) a[i] = *(const bf16x8*)&As[(wm + i * 16 + lr) * 32 + lg * 8];
#pragma unroll
        for (int i = 0; i < 4; ++i) b[i] = *(const bf16x8*)&Bs[(wn + i * 16 + lr) * 32 + lg * 8];
#pragma unroll
        for (int mi = 0; mi < 4; ++mi)
#pragma unroll
            for (int ni = 0; ni < 4; ++ni)
                acc[mi][ni] = __builtin_amdgcn_mfma_f32_16x16x32_bf16(a[mi], b[ni], acc[mi][ni], 0, 0, 0);
    }

#pragma unroll
    for (int mi = 0; mi < 4; ++mi)
#pragma unroll
        for (int ni = 0; ni < 4; ++ni) {
            const int col = n0 + wn + ni * 16 + lr;
            const float bb = bias[col];
#pragma unroll
            for (int r = 0; r < 4; ++r) {
                const int row = m0 + wm + mi * 16 + lg * 4 + r;
                ofp[(u64)row * DIM + col] = acc[mi][ni][r] + bb;
            }
        }
}

// ---------------- Flash attention, swapped-QK^T, 4 waves x 32 q, KVBLK=64 ----------------
__global__ __launch_bounds__(256) void attn_kernel(
    const u16* __restrict__ Qb, const u16* __restrict__ Kb, const u16* __restrict__ Vt,
    const int* __restrict__ mask, u16* __restrict__ ctx)
{
    __shared__ __align__(16) u16 Ks[2][64 * 64];     // [krow][d], XOR-swizzled image
    __shared__ __align__(16) u16 Vs[2][64 * 64];     // [d][k],   XOR-swizzled image
    __shared__ __align__(16) u16 Pl[4][32 * 72];     // per-wave P [qlocal][k], stride 72

    const int t = threadIdx.x;
    const int w = t >> 6, lane = t & 63;
    const int lr = lane & 15, lg = lane >> 4;
    const int bh = blockIdx.y;
    const int b = bh >> 4, hh = bh & 15;
    const int q0 = blockIdx.x * 128;
    const u16* Kbh = Kb + (u64)bh * QLEN * DH;
    const u16* Vth = Vt + (u64)bh * DH * QLEN;
    const int* mb = mask + b * QLEN;

    // Q fragments (B-operand): q = lr, d = kk*32 + lg*8
    bf16x8 aq[2][2];
#pragma unroll
    for (int qa = 0; qa < 2; ++qa)
#pragma unroll
        for (int kk = 0; kk < 2; ++kk)
            aq[qa][kk] = *(const bf16x8*)&Qb[((u64)bh * QLEN + q0 + w * 32 + qa * 16 + lr) * DH + kk * 32 + lg * 8];

    f32x4 o[2][4] = {};
    float m[2] = {-3.0e38f, -3.0e38f};
    float lsum[2] = {0.f, 0.f};

    const int srow = lane >> 3;
    const int schunk = lane & 7;

#define STAGE(BUF, KT) do {                                                            \
    _Pragma("unroll")                                                                  \
    for (int c = 0; c < 2; ++c) {                                                      \
        const int row_ = c * 32 + w * 8 + srow;                                        \
        const int ch_ = schunk ^ (row_ & 7);                                           \
        async_lds16(Kbh + (u64)((KT) + row_) * DH + ch_ * 8, &Ks[BUF][(c * 32 + w * 8) * 64]); \
        async_lds16(Vth + (u64)row_ * QLEN + (KT) + ch_ * 8, &Vs[BUF][(c * 32 + w * 8) * 64]); \
    } } while (0)

    STAGE(0, 0);
    __syncthreads();

    int buf = 0;
    for (int kt = 0; kt < QLEN; kt += 64) {
        if (kt + 64 < QLEN) STAGE(buf ^ 1, kt + 64);

        // S^T = K Q^T : s[qa][nf] holds S[q=lr][k = kt + nf*16 + lg*4 + r]
        f32x4 s[2][4] = {};
#pragma unroll
        for (int nf = 0; nf < 4; ++nf) {
            const int row = nf * 16 + lr;
#pragma unroll
            for (int kk = 0; kk < 2; ++kk) {
                const u32 off = ((u32)(row * 128 + kk * 64 + lg * 16)) ^ ((u32)(row & 7) << 4);
                bf16x8 ak = *(const bf16x8*)((const char*)&Ks[buf][0] + off);
                s[0][nf] = __builtin_amdgcn_mfma_f32_16x16x32_bf16(ak, aq[0][kk], s[0][nf], 0, 0, 0);
                s[1][nf] = __builtin_amdgcn_mfma_f32_16x16x32_bf16(ak, aq[1][kk], s[1][nf], 0, 0, 0);
            }
        }

        int4 mv[4];
#pragma unroll
        for (int nf = 0; nf < 4; ++nf) mv[nf] = *(const int4*)&mb[kt + nf * 16 + lg * 4];

#pragma unroll
        for (int qa = 0; qa < 2; ++qa) {
            // row max over this lane's 16 k-values, then across the 4 lg-lanes
            float tm = s[qa][0][0];
#pragma unroll
            for (int nf = 0; nf < 4; ++nf)
#pragma unroll
                for (int r = 0; r < 4; ++r) tm = fmaxf(tm, s[qa][nf][r]);
            tm = fmaxf(tm, __shfl_xor(tm, 16));
            tm = fmaxf(tm, __shfl_xor(tm, 32));

            if (!__all(tm <= m[qa] + 8.0f)) {       // rescale (rare; always on tile 0)
                const float nm = fmaxf(m[qa], tm);
                const float corr = __expf(m[qa] - nm);
                m[qa] = nm;
                lsum[qa] *= corr;
#pragma unroll
                for (int r = 0; r < 4; ++r) {
                    const float cT = __shfl(corr, lg * 4 + r);
#pragma unroll
                    for (int nf2 = 0; nf2 < 4; ++nf2) o[qa][nf2][r] *= cT;
                }
            }

            // P = mask ? exp(S - m) : 0 ; accumulate per-lane partial sum; pack to LDS
            float ps = 0.f;
#pragma unroll
            for (int nf = 0; nf < 4; ++nf) {
                float p[4];
#pragma unroll
                for (int r = 0; r < 4; ++r) {
                    const int mvr = r == 0 ? mv[nf].x : r == 1 ? mv[nf].y : r == 2 ? mv[nf].z : mv[nf].w;
                    const float e = __expf(s[qa][nf][r] - m[qa]);
                    p[r] = mvr ? e : 0.f;
                    ps += p[r];
                }
                uint2 pk;
                pk.x = cvtpk_bf16(p[0], p[1]);
                pk.y = cvtpk_bf16(p[2], p[3]);
                *(uint2*)&Pl[w][(qa * 16 + lr) * 72 + nf * 16 + lg * 4] = pk;
            }
            lsum[qa] += ps;
        }

        // P A-fragments (both q-subtiles)
        bf16x8 ap[2][2];
#pragma unroll
        for (int qa = 0; qa < 2; ++qa)
#pragma unroll
            for (int kk = 0; kk < 2; ++kk)
                ap[qa][kk] = *(const bf16x8*)&Pl[w][(qa * 16 + lr) * 72 + kk * 32 + lg * 8];

        // O += P V : V fragment loaded once, used for both q-subtiles
#pragma unroll
        for (int nf2 = 0; nf2 < 4; ++nf2) {
            const int row = nf2 * 16 + lr;
#pragma unroll
            for (int kk = 0; kk < 2; ++kk) {
                const u32 off = ((u32)(row * 128 + kk * 64 + lg * 16)) ^ ((u32)(row & 7) << 4);
                bf16x8 bv = *(const bf16x8*)((const char*)&Vs[buf][0] + off);
                o[0][nf2] = __builtin_amdgcn_mfma_f32_16x16x32_bf16(ap[0][kk], bv, o[0][nf2], 0, 0, 0);
                o[1][nf2] = __builtin_amdgcn_mfma_f32_16x16x32_bf16(ap[1][kk], bv, o[1][nf2], 0, 0, 0);
            }
        }

        __syncthreads();
        buf ^= 1;
    }

    // epilogue: reduce l across lg-lanes, normalize, write ctx[b][q][h][d]
#pragma unroll
    for (int qa = 0; qa < 2; ++qa) {
        float l = lsum[qa];
        l += __shfl_xor(l, 16);
        l += __shfl_xor(l, 32);
        const float inv = 1.0f / fmaxf(l, 1e-37f);
#pragma unroll
        for (int r = 0; r < 4; ++r) {
            const float iT = __shfl(inv, lg * 4 + r);
            const int q = q0 + w * 32 + qa * 16 + lg * 4 + r;
#pragma unroll
            for (int nf2 = 0; nf2 < 4; ++nf2) {
                const int d = nf2 * 16 + lr;
                ctx[(((u64)b * QLEN + q) * NH + hh) * DH + d] = f2bf_hw(o[qa][nf2][r] * iT);
            }
        }
    }
#undef STAGE
}

extern "C" void kernel_launch(void* const* d_in, const int* in_sizes, int n_in,
                              void* d_out, int out_size, void* d_ws, size_t ws_size,
                              hipStream_t stream) {
    const float* H    = (const float*)d_in[0];
    const int*   mask = (const int*)d_in[1];
    const float* Wq   = (const float*)d_in[2];
    const float* bq   = (const float*)d_in[3];
    const float* Wk   = (const float*)d_in[4];
    const float* bk   = (const float*)d_in[5];
    const float* Wv   = (const float*)d_in[6];
    const float* bv   = (const float*)d_in[7];
    const float* Wo   = (const float*)d_in[8];
    const float* bo   = (const float*)d_in[9];
    float* out = (float*)d_out;

    const u64 NTOK = (u64)BS * QLEN;        // 8192
    const u64 HN = NTOK * DIM;              // 8388608
    const u64 WN = (u64)DIM * DIM;          // 1048576

    u16* Hb  = (u16*)d_ws;
    u16* Wqb = Hb + HN;
    u16* Wkb = Wqb + WN;
    u16* Wvb = Wkb + WN;
    u16* Wob = Wvb + WN;
    u16* Qb  = Wob + WN;
    u16* Kb  = Qb + HN;
    u16* Vtg = Kb + HN;   // V stored transposed [bh][d][q]
    u16* Ctx = Vtg + HN;

    cvt_fused<<<12288, 256, 0, stream>>>(H, Wq, Wk, Wv, Wo, Hb, Wqb, Wkb, Wvb, Wob);

    gemm_qkv<<<dim3(DIM / 128, (int)(NTOK / 128), 3), 256, 0, stream>>>(
        Hb, Wqb, Wkb, Wvb, bq, bk, bv, Qb, Kb, Vtg);

    attn_kernel<<<dim3(QLEN / 128, BS * NH), 256, 0, stream>>>(Qb, Kb, Vtg, mask, Ctx);

    gemm_o<<<dim3(DIM / 128, (int)(NTOK / 128)), 256, 0, stream>>>(Ctx, Wob, bo, out);
}